// Round 1
// 847.906 us; speedup vs baseline: 1.7762x; 1.7762x over previous
//
#include <hip/hip_runtime.h>
#include <math.h>

#define T_LEN 51200
#define BATCH 1024
#define HDIM 128
#define NIT 100000
#define NTILE 1563   // ceil(100000 / 64)

typedef __attribute__((ext_vector_type(8))) short bf16x8;
typedef __attribute__((ext_vector_type(16))) float f32x16;

// float -> bf16 round-to-nearest-even (bit trick; no NaN inputs here)
__device__ __forceinline__ unsigned short f2bf_rne(float f) {
    unsigned x = __float_as_uint(f);
    unsigned r = x + 0x7FFFu + ((x >> 16) & 1u);
    return (unsigned short)(r >> 16);
}

__device__ __forceinline__ int lower_bound_i(const int* __restrict__ a, int n, int v) {
    int lo = 0, hi = n;
    while (lo < hi) { int m = (lo + hi) >> 1; if (a[m] < v) lo = m + 1; else hi = m; }
    return lo;
}

// One block per batch row; 128 threads = one per feature.
// Emits user row as split bf16 (hi + lo) for the MFMA passes; zero-inits row sums.
__global__ __launch_bounds__(128) void pool_kernel(
    const int* __restrict__ item_idx, const int* __restrict__ item_seg,
    const int* __restrict__ ent_idx,  const int* __restrict__ ent_seg,
    const int* __restrict__ word_idx, const int* __restrict__ word_seg,
    const float* __restrict__ item_tab, const float* __restrict__ ent_tab,
    const float* __restrict__ word_tab,
    unsigned short* __restrict__ Uhi, unsigned short* __restrict__ Ulo,
    float* __restrict__ sums, float* __restrict__ s2m)
{
    const int b = blockIdx.x;
    const int h = threadIdx.x;
    float acc = 0.f;
    {
        int lo = lower_bound_i(item_seg, T_LEN, b);
        int hi = lower_bound_i(item_seg, T_LEN, b + 1);
        float s = 0.f;
        for (int t = lo; t < hi; ++t) s += item_tab[(size_t)item_idx[t] * HDIM + h];
        if (hi > lo) acc += s / (float)(hi - lo);
    }
    {
        int lo = lower_bound_i(ent_seg, T_LEN, b);
        int hi = lower_bound_i(ent_seg, T_LEN, b + 1);
        float s = 0.f;
        for (int t = lo; t < hi; ++t) s += ent_tab[(size_t)ent_idx[t] * HDIM + h];
        if (hi > lo) acc += s / (float)(hi - lo);
    }
    {
        int lo = lower_bound_i(word_seg, T_LEN, b);
        int hi = lower_bound_i(word_seg, T_LEN, b + 1);
        float s = 0.f;
        for (int t = lo; t < hi; ++t) s += word_tab[(size_t)word_idx[t] * HDIM + h];
        if (hi > lo) acc += s / (float)(hi - lo);
    }
    float v = acc * (1.f / 3.f);
    unsigned short hb = f2bf_rne(v);
    float hf = __uint_as_float((unsigned)hb << 16);
    unsigned short lb2 = f2bf_rne(v - hf);
    Uhi[b * HDIM + h] = hb;
    Ulo[b * HDIM + h] = lb2;
    if (h == 0) { sums[b] = 0.f; s2m[b] = 0.f; }
}

// MFMA GEMM over user(1024x128) x W(128x100000), K=128 fully unrolled in
// 8 steps of v_mfma_f32_32x32x16_bf16. U split hi/lo bf16 (2 MFMA terms),
// W rounded RNE to bf16 on the fly from the f32 weights.
//
// Layout-proofing: both A and B fragments are loaded with the SAME chosen
// k-order (k = k0 + 8*(lane>>5) + j). A-row / B-col = lane&31 are mirror
// images for this instruction, so the contraction is correct regardless of
// the hardware's internal k-permutation. C/D mapping (HW-verified):
// col = lane&31, row = (reg&3) + 8*(reg>>2) + 4*(lane>>5).
//
// PASS 1 (swapped: D = W^T-frag * U-frag -> D[n][m]): each lane holds full
// n-slices for ONE m column => per-row sums S1=sum(e), S2=sum(e^2) reduce
// in-register; one cross-half shuffle + atomics. No stores of lin.
// PASS 2 (normal: D = U-frag * W-frag -> D[m][n]): writes
// probs = exp(lin)/S1 with coalesced nontemporal dword stores.
template<int PASS>
__global__ __launch_bounds__(256) void gemm_pass(
    const unsigned short* __restrict__ Uhi, const unsigned short* __restrict__ Ulo,
    const float* __restrict__ W, const float* __restrict__ bias,
    const float* __restrict__ rinvp, float* __restrict__ probs,
    float* __restrict__ sums, float* __restrict__ s2m)
{
    const int tid  = threadIdx.x;
    const int wid  = tid >> 6;
    const int lane = tid & 63;
    const int l31  = lane & 31;
    const int half = lane >> 5;
    const int m0   = blockIdx.y * 256 + wid * 64;   // this wave's 64 m-rows

    const unsigned short* uh0 = Uhi + (m0 + l31) * HDIM + 8 * half;
    const unsigned short* ul0 = Ulo + (m0 + l31) * HDIM + 8 * half;

    float s1[2]  = {0.f, 0.f};
    float s2v[2] = {0.f, 0.f};

    const int nIt = (PASS == 1) ? 4 : 1;
    for (int it = 0; it < nIt; ++it) {
        const int nj = (PASS == 1) ? (blockIdx.x * 4 + it) : blockIdx.x;
        if (nj >= NTILE) break;
        const int n0  = nj * 64;
        const int nc0 = n0 + l31;
        const int nc1 = n0 + 32 + l31;
        // clamp tail columns into bounds; results for them are masked later
        const float* wb0 = W + 8 * half * NIT + min(nc0, NIT - 1);
        const float* wb1 = W + 8 * half * NIT + min(nc1, NIT - 1);

        f32x16 acc[2][2];   // [A-subtile][B-subtile]
        #pragma unroll
        for (int i = 0; i < 2; ++i)
            #pragma unroll
            for (int j = 0; j < 2; ++j)
                #pragma unroll
                for (int r = 0; r < 16; ++r) acc[i][j][r] = 0.f;

        #pragma unroll
        for (int s = 0; s < 8; ++s) {
            bf16x8 uh[2], ul[2], wf[2];
            #pragma unroll
            for (int mt = 0; mt < 2; ++mt) {
                uh[mt] = *(const bf16x8*)(uh0 + mt * 32 * HDIM + 16 * s);
                ul[mt] = *(const bf16x8*)(ul0 + mt * 32 * HDIM + 16 * s);
            }
            const float* wp0 = wb0 + 16 * s * NIT;
            const float* wp1 = wb1 + 16 * s * NIT;
            #pragma unroll
            for (int j = 0; j < 8; ++j) {
                wf[0][j] = (short)f2bf_rne(wp0[j * NIT]);
                wf[1][j] = (short)f2bf_rne(wp1[j * NIT]);
            }
            #pragma unroll
            for (int i = 0; i < 2; ++i)
                #pragma unroll
                for (int j = 0; j < 2; ++j) {
                    if (PASS == 1) {   // A = W (rows = n), B = U (cols = m)
                        acc[i][j] = __builtin_amdgcn_mfma_f32_32x32x16_bf16(wf[i], ul[j], acc[i][j], 0, 0, 0);
                        acc[i][j] = __builtin_amdgcn_mfma_f32_32x32x16_bf16(wf[i], uh[j], acc[i][j], 0, 0, 0);
                    } else {           // A = U (rows = m), B = W (cols = n)
                        acc[i][j] = __builtin_amdgcn_mfma_f32_32x32x16_bf16(ul[i], wf[j], acc[i][j], 0, 0, 0);
                        acc[i][j] = __builtin_amdgcn_mfma_f32_32x32x16_bf16(uh[i], wf[j], acc[i][j], 0, 0, 0);
                    }
                }
        }

        if (PASS == 1) {
            #pragma unroll
            for (int i = 0; i < 2; ++i)          // n-subtile (C rows = n)
                #pragma unroll
                for (int r = 0; r < 16; ++r) {
                    const int nrow = n0 + 32 * i + (r & 3) + 8 * (r >> 2) + 4 * half;
                    const bool ok = nrow < NIT;
                    const float bv = bias[ok ? nrow : 0];
                    float e0 = ok ? __expf(acc[i][0][r] + bv) : 0.f;
                    float e1 = ok ? __expf(acc[i][1][r] + bv) : 0.f;
                    s1[0] += e0; s2v[0] += e0 * e0;
                    s1[1] += e1; s2v[1] += e1 * e1;
                }
        } else {
            const bool ok0 = nc0 < NIT, ok1 = nc1 < NIT;
            const float b0 = bias[min(nc0, NIT - 1)];
            const float b1 = bias[min(nc1, NIT - 1)];
            #pragma unroll
            for (int i = 0; i < 2; ++i)          // m-subtile (C rows = m)
                #pragma unroll
                for (int r = 0; r < 16; ++r) {
                    const int row = m0 + 32 * i + (r & 3) + 8 * (r >> 2) + 4 * half;
                    const float ri = rinvp[row];
                    if (ok0) {
                        float p = __expf(acc[i][0][r] + b0) * ri;
                        __builtin_nontemporal_store(p, &probs[(size_t)row * NIT + nc0]);
                    }
                    if (ok1) {
                        float p = __expf(acc[i][1][r] + b1) * ri;
                        __builtin_nontemporal_store(p, &probs[(size_t)row * NIT + nc1]);
                    }
                }
        }
    }

    if (PASS == 1) {
        #pragma unroll
        for (int mt = 0; mt < 2; ++mt) {
            float a1 = s1[mt]  + __shfl_xor(s1[mt], 32);
            float a2 = s2v[mt] + __shfl_xor(s2v[mt], 32);
            if (half == 0) {
                atomicAdd(&sums[m0 + 32 * mt + l31], a1);
                atomicAdd(&s2m [m0 + 32 * mt + l31], a2);
            }
        }
    }
}

__global__ __launch_bounds__(256) void rinv_kernel(const float* __restrict__ sums,
                                                   float* __restrict__ rinvp)
{
    int b = blockIdx.x * 256 + threadIdx.x;
    if (b < BATCH) rinvp[b] = 1.0f / sums[b];
}

// loss; sums2 via exact series: sum(exp(p)) = NIT + sum(p) + sum(p^2)/2 + O(p^3)
//                              = NIT + 1 + S2/(2*S1^2)   (p ~ 1e-5 => O(p^3) ~ 1e-11)
__global__ __launch_bounds__(256) void loss_kernel(
    const float* __restrict__ probs, const int* __restrict__ labels,
    const float* __restrict__ s2m, const float* __restrict__ rinvp,
    float* __restrict__ out)
{
    __shared__ float red[256];
    float t = 0.f;
    for (int b = threadIdx.x; b < BATCH; b += 256) {
        int lab = labels[b];
        float p = probs[(size_t)b * NIT + lab];
        float ri = rinvp[b];
        float sums2 = (float)NIT + 1.0f + 0.5f * s2m[b] * ri * ri;
        t += p - logf(sums2);
        out[(size_t)BATCH * NIT + b] = (float)lab;  // labels output as f32
    }
    red[threadIdx.x] = t;
    __syncthreads();
    for (int s = 128; s > 0; s >>= 1) {
        if (threadIdx.x < s) red[threadIdx.x] += red[threadIdx.x + s];
        __syncthreads();
    }
    if (threadIdx.x == 0) out[(size_t)BATCH * NIT + BATCH] = -red[0] / (float)BATCH;
}

extern "C" void kernel_launch(void* const* d_in, const int* in_sizes, int n_in,
                              void* d_out, int out_size, void* d_ws, size_t ws_size,
                              hipStream_t stream)
{
    const int* item_idx = (const int*)d_in[0];
    const int* item_seg = (const int*)d_in[1];
    const int* ent_idx  = (const int*)d_in[2];
    const int* ent_seg  = (const int*)d_in[3];
    const int* word_idx = (const int*)d_in[4];
    const int* word_seg = (const int*)d_in[5];
    const int* labels   = (const int*)d_in[6];
    const float* item_tab = (const float*)d_in[7];
    const float* ent_tab  = (const float*)d_in[8];
    const float* word_tab = (const float*)d_in[9];
    const float* rec_w    = (const float*)d_in[10];
    const float* rec_b    = (const float*)d_in[11];
    float* out = (float*)d_out;

    // workspace: 2*256KB bf16 user + 3*4KB row stats = ~524 KB
    unsigned short* Uhi = (unsigned short*)d_ws;
    unsigned short* Ulo = Uhi + BATCH * HDIM;
    float* sums  = (float*)(Ulo + BATCH * HDIM);
    float* s2m   = sums + BATCH;
    float* rinvp = s2m + BATCH;

    pool_kernel<<<BATCH, 128, 0, stream>>>(item_idx, item_seg, ent_idx, ent_seg,
                                           word_idx, word_seg, item_tab, ent_tab,
                                           word_tab, Uhi, Ulo, sums, s2m);

    gemm_pass<1><<<dim3(391, 4), 256, 0, stream>>>(Uhi, Ulo, rec_w, rec_b,
                                                   rinvp, out, sums, s2m);

    rinv_kernel<<<4, 256, 0, stream>>>(sums, rinvp);

    gemm_pass<2><<<dim3(NTILE, 4), 256, 0, stream>>>(Uhi, Ulo, rec_w, rec_b,
                                                     rinvp, out, sums, s2m);

    loss_kernel<<<1, 256, 0, stream>>>(out, labels, s2m, rinvp, out);
}

// Round 3
// 670.264 us; speedup vs baseline: 2.2470x; 1.2650x over previous
//
#include <hip/hip_runtime.h>
#include <math.h>

#define T_LEN 51200
#define BATCH 1024
#define HDIM 128
#define NIT 100000
#define NTILE 1563   // ceil(100000 / 64)
#define TI 4         // n-tiles per gemm block

typedef __attribute__((ext_vector_type(8))) short bf16x8;
typedef __attribute__((ext_vector_type(16))) float f32x16;

// float -> bf16 round-to-nearest-even (bit trick; no NaN inputs here)
__device__ __forceinline__ unsigned short f2bf_rne(float f) {
    unsigned x = __float_as_uint(f);
    unsigned r = x + 0x7FFFu + ((x >> 16) & 1u);
    return (unsigned short)(r >> 16);
}

__device__ __forceinline__ int lower_bound_i(const int* __restrict__ a, int n, int v) {
    int lo = 0, hi = n;
    while (lo < hi) { int m = (lo + hi) >> 1; if (a[m] < v) lo = m + 1; else hi = m; }
    return lo;
}

// async global->LDS, 16B per lane (linear LDS dest = wave base + lane*16)
__device__ __forceinline__ void stage16(const void* g, void* l) {
#if __has_builtin(__builtin_amdgcn_global_load_lds)
    __builtin_amdgcn_global_load_lds(
        (const __attribute__((address_space(1))) unsigned int*)g,
        (__attribute__((address_space(3))) unsigned int*)l, 16, 0, 0);
#else
    *(float4*)l = *(const float4*)g;
#endif
}

// One block per batch row; 3 x 128 threads = one 128-group per table (3x the
// latency parallelism of the serial version). LDS combine, then bf16 split.
__global__ __launch_bounds__(384) void pool_kernel(
    const int* __restrict__ item_idx, const int* __restrict__ item_seg,
    const int* __restrict__ ent_idx,  const int* __restrict__ ent_seg,
    const int* __restrict__ word_idx, const int* __restrict__ word_seg,
    const float* __restrict__ item_tab, const float* __restrict__ ent_tab,
    const float* __restrict__ word_tab,
    unsigned short* __restrict__ Uhi, unsigned short* __restrict__ Ulo,
    float* __restrict__ sums, float* __restrict__ s2m)
{
    __shared__ float part[3][128];
    const int b   = blockIdx.x;
    const int tbl = threadIdx.x >> 7;
    const int h   = threadIdx.x & 127;
    const int*   idx = (tbl == 0) ? item_idx : (tbl == 1) ? ent_idx : word_idx;
    const int*   seg = (tbl == 0) ? item_seg : (tbl == 1) ? ent_seg : word_seg;
    const float* tab = (tbl == 0) ? item_tab : (tbl == 1) ? ent_tab : word_tab;

    const int lo = lower_bound_i(seg, T_LEN, b);
    const int hi = lower_bound_i(seg, T_LEN, b + 1);
    float s = 0.f;
    for (int t = lo; t < hi; ++t) s += tab[(size_t)idx[t] * HDIM + h];
    part[tbl][h] = (hi > lo) ? s / (float)(hi - lo) : 0.f;
    __syncthreads();

    if (threadIdx.x < 128) {
        float v = (part[0][h] + part[1][h] + part[2][h]) * (1.f / 3.f);
        unsigned short hb = f2bf_rne(v);
        float hf = __uint_as_float((unsigned)hb << 16);
        Uhi[b * HDIM + h] = hb;
        Ulo[b * HDIM + h] = f2bf_rne(v - hf);
        if (h == 0) { sums[b] = 0.f; s2m[b] = 0.f; }
    }
}

// W (f32, [k][n] row-major, k=128) -> Wt (bf16, per-64-n-tile contiguous 16KB
// blocks, n-major [n][k], XOR-swizzle baked: byte-in-row ^= (n&7)<<4).
// One block per n-tile; coalesced f32 reads, LDS transpose, linear 16KB dump.
__global__ __launch_bounds__(256) void wconv_kernel(
    const float* __restrict__ W, unsigned short* __restrict__ Wt)
{
    __shared__ unsigned short tile[8192];  // 16 KB, swizzled [n][k]
    const int nj = blockIdx.x;
    const int n0 = nj * 64;
    const int n  = threadIdx.x & 63;
    const int kk = threadIdx.x >> 6;       // 0..3
    const int col = min(n0 + n, NIT - 1);  // clamp tail (masked downstream)

    #pragma unroll
    for (int j = 0; j < 32; ++j) {
        const int k = kk * 32 + j;
        float v = W[(size_t)k * NIT + col];
        int a = (n * 256 + k * 2) ^ ((n & 7) << 4);
        *(unsigned short*)((char*)tile + a) = f2bf_rne(v);
    }
    __syncthreads();

    float4* dst = (float4*)(Wt + (size_t)nj * 8192);
    const float4* src = (const float4*)tile;
    #pragma unroll
    for (int r = 0; r < 4; ++r) dst[threadIdx.x + r * 256] = src[threadIdx.x + r * 256];
}

// MFMA GEMM, bf16 U (hi only; W is bf16 so the dropped U-lo term changes lin
// by ~4e-5 rel -> probs by ~5e-10 abs, far under tolerance) x preconverted Wt.
// Per block: 4 waves x 64 m-rows, TI n-tiles, double-buffered 16KB LDS W tile
// via global_load_lds, one barrier per tile, barriers unconditionally executed
// by ALL threads every iteration (no break; bodies guarded block-uniformly).
// Fragment k-order identical on both operands => layout-permutation-proof.
// C/D mapping: col=lane&31, row=(reg&3)+8*(reg>>2)+4*(lane>>5).
// PASS 1 (swapped, D[n][m]): in-register row sums S1, S2, no stores.
// PASS 2 (D[m][n]): probs = exp(lin)/S1, coalesced nontemporal stores.
template<int PASS>
__global__ __launch_bounds__(256) void gemm_fast(
    const unsigned short* __restrict__ Uhi, const unsigned short* __restrict__ Wt,
    const float* __restrict__ bias, float* __restrict__ probs,
    float* __restrict__ sums, float* __restrict__ s2m)
{
    __shared__ unsigned short wt[2][8192];
    const int tid  = threadIdx.x;
    const int wid  = tid >> 6;
    const int lane = tid & 63;
    const int l31  = lane & 31;
    const int half = lane >> 5;
    const int m0   = blockIdx.y * 256 + wid * 64;

    // hoisted U fragments (k = 16s + 8*half + j), reused for all TI tiles
    bf16x8 uh[2][8];
    #pragma unroll
    for (int mt = 0; mt < 2; ++mt)
        #pragma unroll
        for (int s = 0; s < 8; ++s)
            uh[mt][s] = *(const bf16x8*)(Uhi + (size_t)(m0 + mt * 32 + l31) * HDIM + 16 * s + 8 * half);

    float ri[2][16];
    if (PASS == 2) {
        #pragma unroll
        for (int i = 0; i < 2; ++i)
            #pragma unroll
            for (int r = 0; r < 16; ++r)
                ri[i][r] = 1.0f / sums[m0 + 32 * i + (r & 3) + 8 * (r >> 2) + 4 * half];
    }

    float s1[2] = {0.f, 0.f}, s2v[2] = {0.f, 0.f};
    const int t0 = blockIdx.x * TI;
    int cur = 0;

    {   // prologue stage of tile t0 into buf 0 (t0 < NTILE always: 390*4=1560)
        const char* g = (const char*)(Wt + (size_t)t0 * 8192) + tid * 16;
        char* l = (char*)&wt[0][0] + tid * 16;
        #pragma unroll
        for (int r2 = 0; r2 < 4; ++r2) stage16(g + r2 * 4096, l + r2 * 4096);
    }

    #pragma unroll
    for (int it = 0; it < TI; ++it) {
        const int nj = t0 + it;               // block-uniform
        const bool active = (nj < NTILE);     // block-uniform
        __syncthreads();                      // wt[cur] staged; prior reads of wt[cur^1] done

        if (it + 1 < TI && nj + 1 < NTILE) {  // block-uniform prefetch
            const char* g = (const char*)(Wt + (size_t)(nj + 1) * 8192) + tid * 16;
            char* l = (char*)&wt[cur ^ 1][0] + tid * 16;
            #pragma unroll
            for (int r2 = 0; r2 < 4; ++r2) stage16(g + r2 * 4096, l + r2 * 4096);
        }

        if (active) {
            f32x16 acc[2][2];
            #pragma unroll
            for (int i = 0; i < 2; ++i)
                #pragma unroll
                for (int j = 0; j < 2; ++j)
                    #pragma unroll
                    for (int r = 0; r < 16; ++r) acc[i][j][r] = 0.f;

            #pragma unroll
            for (int s = 0; s < 8; ++s) {
                bf16x8 wf[2];
                #pragma unroll
                for (int nt = 0; nt < 2; ++nt) {
                    int a = ((nt * 32 + l31) * 256 + 32 * s + 16 * half) ^ ((l31 & 7) << 4);
                    wf[nt] = *(const bf16x8*)((const char*)&wt[cur][0] + a);
                }
                #pragma unroll
                for (int i = 0; i < 2; ++i)
                    #pragma unroll
                    for (int j = 0; j < 2; ++j) {
                        if (PASS == 1)
                            acc[i][j] = __builtin_amdgcn_mfma_f32_32x32x16_bf16(wf[i], uh[j][s], acc[i][j], 0, 0, 0);
                        else
                            acc[i][j] = __builtin_amdgcn_mfma_f32_32x32x16_bf16(uh[i][s], wf[j], acc[i][j], 0, 0, 0);
                    }
            }

            const int n0 = nj * 64;
            if (PASS == 1) {
                #pragma unroll
                for (int i = 0; i < 2; ++i)
                    #pragma unroll
                    for (int r = 0; r < 16; ++r) {
                        const int nrow = n0 + 32 * i + (r & 3) + 8 * (r >> 2) + 4 * half;
                        const bool ok = nrow < NIT;
                        const float bv = bias[ok ? nrow : 0];
                        float e0 = ok ? __expf(acc[i][0][r] + bv) : 0.f;
                        float e1 = ok ? __expf(acc[i][1][r] + bv) : 0.f;
                        s1[0] += e0; s2v[0] += e0 * e0;
                        s1[1] += e1; s2v[1] += e1 * e1;
                    }
            } else {
                const int nc0 = n0 + l31, nc1 = n0 + 32 + l31;
                const bool ok0 = nc0 < NIT, ok1 = nc1 < NIT;
                const float b0 = bias[min(nc0, NIT - 1)];
                const float b1 = bias[min(nc1, NIT - 1)];
                #pragma unroll
                for (int i = 0; i < 2; ++i)
                    #pragma unroll
                    for (int r = 0; r < 16; ++r) {
                        const int row = m0 + 32 * i + (r & 3) + 8 * (r >> 2) + 4 * half;
                        if (ok0) {
                            float p = __expf(acc[i][0][r] + b0) * ri[i][r];
                            __builtin_nontemporal_store(p, &probs[(size_t)row * NIT + nc0]);
                        }
                        if (ok1) {
                            float p = __expf(acc[i][1][r] + b1) * ri[i][r];
                            __builtin_nontemporal_store(p, &probs[(size_t)row * NIT + nc1]);
                        }
                    }
            }
        }
        cur ^= 1;
    }

    if (PASS == 1) {
        #pragma unroll
        for (int mt = 0; mt < 2; ++mt) {
            float a1 = s1[mt]  + __shfl_xor(s1[mt], 32);
            float a2 = s2v[mt] + __shfl_xor(s2v[mt], 32);
            if (half == 0) {
                atomicAdd(&sums[m0 + 32 * mt + l31], a1);
                atomicAdd(&s2m [m0 + 32 * mt + l31], a2);
            }
        }
    }
}

// ---------------- fallback path (verified round-1 kernels, used if ws too small) ----------------
template<int PASS>
__global__ __launch_bounds__(256) void gemm_slow(
    const unsigned short* __restrict__ Uhi, const unsigned short* __restrict__ Ulo,
    const float* __restrict__ W, const float* __restrict__ bias,
    const float* __restrict__ rinvp, float* __restrict__ probs,
    float* __restrict__ sums, float* __restrict__ s2m)
{
    const int tid  = threadIdx.x;
    const int wid  = tid >> 6;
    const int lane = tid & 63;
    const int l31  = lane & 31;
    const int half = lane >> 5;
    const int m0   = blockIdx.y * 256 + wid * 64;

    const unsigned short* uh0 = Uhi + (m0 + l31) * HDIM + 8 * half;
    const unsigned short* ul0 = Ulo + (m0 + l31) * HDIM + 8 * half;

    float s1[2] = {0.f, 0.f}, s2v[2] = {0.f, 0.f};
    const int nIt = (PASS == 1) ? 4 : 1;
    for (int it = 0; it < nIt; ++it) {
        const int nj = (PASS == 1) ? (blockIdx.x * 4 + it) : blockIdx.x;
        if (nj >= NTILE) break;
        const int n0  = nj * 64;
        const int nc0 = n0 + l31, nc1 = n0 + 32 + l31;
        const float* wb0 = W + 8 * half * NIT + min(nc0, NIT - 1);
        const float* wb1 = W + 8 * half * NIT + min(nc1, NIT - 1);

        f32x16 acc[2][2];
        #pragma unroll
        for (int i = 0; i < 2; ++i)
            #pragma unroll
            for (int j = 0; j < 2; ++j)
                #pragma unroll
                for (int r = 0; r < 16; ++r) acc[i][j][r] = 0.f;

        #pragma unroll
        for (int s = 0; s < 8; ++s) {
            bf16x8 uh[2], ul[2], wf[2];
            #pragma unroll
            for (int mt = 0; mt < 2; ++mt) {
                uh[mt] = *(const bf16x8*)(uh0 + mt * 32 * HDIM + 16 * s);
                ul[mt] = *(const bf16x8*)(ul0 + mt * 32 * HDIM + 16 * s);
            }
            const float* wp0 = wb0 + 16 * s * NIT;
            const float* wp1 = wb1 + 16 * s * NIT;
            #pragma unroll
            for (int j = 0; j < 8; ++j) {
                wf[0][j] = (short)f2bf_rne(wp0[j * NIT]);
                wf[1][j] = (short)f2bf_rne(wp1[j * NIT]);
            }
            #pragma unroll
            for (int i = 0; i < 2; ++i)
                #pragma unroll
                for (int j = 0; j < 2; ++j) {
                    if (PASS == 1) {
                        acc[i][j] = __builtin_amdgcn_mfma_f32_32x32x16_bf16(wf[i], ul[j], acc[i][j], 0, 0, 0);
                        acc[i][j] = __builtin_amdgcn_mfma_f32_32x32x16_bf16(wf[i], uh[j], acc[i][j], 0, 0, 0);
                    } else {
                        acc[i][j] = __builtin_amdgcn_mfma_f32_32x32x16_bf16(ul[i], wf[j], acc[i][j], 0, 0, 0);
                        acc[i][j] = __builtin_amdgcn_mfma_f32_32x32x16_bf16(uh[i], wf[j], acc[i][j], 0, 0, 0);
                    }
                }
        }

        if (PASS == 1) {
            #pragma unroll
            for (int i = 0; i < 2; ++i)
                #pragma unroll
                for (int r = 0; r < 16; ++r) {
                    const int nrow = n0 + 32 * i + (r & 3) + 8 * (r >> 2) + 4 * half;
                    const bool ok = nrow < NIT;
                    const float bv = bias[ok ? nrow : 0];
                    float e0 = ok ? __expf(acc[i][0][r] + bv) : 0.f;
                    float e1 = ok ? __expf(acc[i][1][r] + bv) : 0.f;
                    s1[0] += e0; s2v[0] += e0 * e0;
                    s1[1] += e1; s2v[1] += e1 * e1;
                }
        } else {
            const bool ok0 = nc0 < NIT, ok1 = nc1 < NIT;
            const float b0 = bias[min(nc0, NIT - 1)];
            const float b1 = bias[min(nc1, NIT - 1)];
            #pragma unroll
            for (int i = 0; i < 2; ++i)
                #pragma unroll
                for (int r = 0; r < 16; ++r) {
                    const int row = m0 + 32 * i + (r & 3) + 8 * (r >> 2) + 4 * half;
                    const float rv = rinvp[row];
                    if (ok0) __builtin_nontemporal_store(__expf(acc[i][0][r] + b0) * rv, &probs[(size_t)row * NIT + nc0]);
                    if (ok1) __builtin_nontemporal_store(__expf(acc[i][1][r] + b1) * rv, &probs[(size_t)row * NIT + nc1]);
                }
        }
    }

    if (PASS == 1) {
        #pragma unroll
        for (int mt = 0; mt < 2; ++mt) {
            float a1 = s1[mt]  + __shfl_xor(s1[mt], 32);
            float a2 = s2v[mt] + __shfl_xor(s2v[mt], 32);
            if (half == 0) {
                atomicAdd(&sums[m0 + 32 * mt + l31], a1);
                atomicAdd(&s2m [m0 + 32 * mt + l31], a2);
            }
        }
    }
}

__global__ __launch_bounds__(256) void rinv_kernel(const float* __restrict__ sums,
                                                   float* __restrict__ rinvp)
{
    int b = blockIdx.x * 256 + threadIdx.x;
    if (b < BATCH) rinvp[b] = 1.0f / sums[b];
}

// loss; sum(exp(p)) = NIT + 1 + S2/(2*S1^2) + O(p^3)  (p ~ 1e-5)
__global__ __launch_bounds__(256) void loss_kernel(
    const float* __restrict__ probs, const int* __restrict__ labels,
    const float* __restrict__ s2m, const float* __restrict__ sums,
    float* __restrict__ out)
{
    __shared__ float red[256];
    float t = 0.f;
    for (int b = threadIdx.x; b < BATCH; b += 256) {
        int lab = labels[b];
        float p = probs[(size_t)b * NIT + lab];
        float ri = 1.0f / sums[b];
        float sums2 = (float)NIT + 1.0f + 0.5f * s2m[b] * ri * ri;
        t += p - logf(sums2);
        out[(size_t)BATCH * NIT + b] = (float)lab;
    }
    red[threadIdx.x] = t;
    __syncthreads();
    for (int s = 128; s > 0; s >>= 1) {
        if (threadIdx.x < s) red[threadIdx.x] += red[threadIdx.x + s];
        __syncthreads();
    }
    if (threadIdx.x == 0) out[(size_t)BATCH * NIT + BATCH] = -red[0] / (float)BATCH;
}

extern "C" void kernel_launch(void* const* d_in, const int* in_sizes, int n_in,
                              void* d_out, int out_size, void* d_ws, size_t ws_size,
                              hipStream_t stream)
{
    const int* item_idx = (const int*)d_in[0];
    const int* item_seg = (const int*)d_in[1];
    const int* ent_idx  = (const int*)d_in[2];
    const int* ent_seg  = (const int*)d_in[3];
    const int* word_idx = (const int*)d_in[4];
    const int* word_seg = (const int*)d_in[5];
    const int* labels   = (const int*)d_in[6];
    const float* item_tab = (const float*)d_in[7];
    const float* ent_tab  = (const float*)d_in[8];
    const float* word_tab = (const float*)d_in[9];
    const float* rec_w    = (const float*)d_in[10];
    const float* rec_b    = (const float*)d_in[11];
    float* out = (float*)d_out;

    const size_t wt_bytes = (size_t)NTILE * 64 * 128 * 2;   // 25.6 MB
    const size_t need = wt_bytes + 2 * (size_t)BATCH * HDIM * 2 + 3 * (size_t)BATCH * 4;
    const bool fast = ws_size >= need;

    unsigned short *Wt, *Uhi, *Ulo;
    if (fast) {
        Wt  = (unsigned short*)d_ws;
        Uhi = (unsigned short*)((char*)d_ws + wt_bytes);
    } else {
        Wt  = nullptr;
        Uhi = (unsigned short*)d_ws;
    }
    Ulo = Uhi + BATCH * HDIM;
    float* sums  = (float*)(Ulo + BATCH * HDIM);
    float* s2m   = sums + BATCH;
    float* rinvp = s2m + BATCH;

    pool_kernel<<<BATCH, 384, 0, stream>>>(item_idx, item_seg, ent_idx, ent_seg,
                                           word_idx, word_seg, item_tab, ent_tab,
                                           word_tab, Uhi, Ulo, sums, s2m);

    if (fast) {
        wconv_kernel<<<NTILE, 256, 0, stream>>>(rec_w, Wt);
        gemm_fast<1><<<dim3(391, 4), 256, 0, stream>>>(Uhi, Wt, rec_b, out, sums, s2m);
        gemm_fast<2><<<dim3(391, 4), 256, 0, stream>>>(Uhi, Wt, rec_b, out, sums, s2m);
    } else {
        gemm_slow<1><<<dim3(391, 4), 256, 0, stream>>>(Uhi, Ulo, rec_w, rec_b,
                                                       rinvp, out, sums, s2m);
        rinv_kernel<<<4, 256, 0, stream>>>(sums, rinvp);
        gemm_slow<2><<<dim3(NTILE, 4), 256, 0, stream>>>(Uhi, Ulo, rec_w, rec_b,
                                                         rinvp, out, sums, s2m);
    }

    loss_kernel<<<1, 256, 0, stream>>>(out, labels, s2m, sums, out);
}